// Round 9
// baseline (1209.798 us; speedup 1.0000x reference)
//
#include <hip/hip_runtime.h>
#include <math.h>

#define SEQ 4096
#define DM  1024

#define BM 128
#define BN 128
#define BK 16
#define PAD 4
#define NCT (SEQ / BN)   // 32 column tiles

typedef unsigned short ushort_t;
union U4 { uint4 u; ushort_t s[8]; };
using short8  = __attribute__((ext_vector_type(8))) short;
using floatx4 = __attribute__((ext_vector_type(4))) float;

__device__ __forceinline__ float bf2f(ushort_t u) {
    return __uint_as_float(((unsigned int)u) << 16);
}
__device__ __forceinline__ ushort_t f2bf(float f) {
    unsigned int u = __float_as_uint(f);
    return (ushort_t)((u + 0x7FFFu + ((u >> 16) & 1u)) >> 16);
}

__device__ __forceinline__ int detect_bf16(const void* p0) {
    const unsigned int* p = (const unsigned int*)p0;
    int cnt = 0;
    #pragma unroll
    for (int i = 0; i < 64; i++) {
        unsigned int e = (p[i] >> 7) & 0xFFu;
        cnt += (e >= 112u && e <= 140u) ? 1 : 0;
    }
    return cnt >= 48 ? 1 : 0;
}

__device__ __forceinline__ void load8(const void* base, size_t idx, int isbf, float* v) {
    if (isbf) {
        U4 t; t.u = *(const uint4*)((const ushort_t*)base + idx);
        #pragma unroll
        for (int q = 0; q < 8; q++) v[q] = bf2f(t.s[q]);
    } else {
        const float* f = (const float*)base + idx;
        float4 a = *(const float4*)f;
        float4 b = *(const float4*)(f + 4);
        v[0] = a.x; v[1] = a.y; v[2] = a.z; v[3] = a.w;
        v[4] = b.x; v[5] = b.y; v[6] = b.z; v[7] = b.w;
    }
}

// ================= ROUND-7 VERIFIED PIPELINE (verbatim) =================

__global__ __launch_bounds__(256)
void proj_q_kernel(const void* __restrict__ X, const void* __restrict__ W,
                   float* __restrict__ C, float scale)
{
    __shared__ float As[BK][BM + PAD];
    __shared__ float Bs[BK][BN + PAD];
    const int isbf = detect_bf16(X);
    const int t  = threadIdx.x;
    const int bx = blockIdx.x;
    const int by = blockIdx.y;
    const int tm = t >> 4, tn = t & 15;

    float acc[8][8];
    #pragma unroll
    for (int i = 0; i < 8; i++)
        #pragma unroll
        for (int j = 0; j < 8; j++) acc[i][j] = 0.f;

    const int ar = t >> 1;
    const int ak = (t & 1) * 8;
    const int wr = t >> 4;
    const int wn = (t & 15) * 8;

    for (int kt = 0; kt < DM; kt += BK) {
        float av[8], wv[8];
        load8(X, (size_t)(by * BM + ar) * DM + kt + ak, isbf, av);
        load8(W, (size_t)(kt + wr) * DM + bx * BN + wn, isbf, wv);
        #pragma unroll
        for (int q = 0; q < 8; q++) As[ak + q][ar] = av[q];
        #pragma unroll
        for (int q = 0; q < 8; q++) Bs[wr][wn + q] = wv[q];
        __syncthreads();
        #pragma unroll
        for (int kk = 0; kk < BK; kk++) {
            float a[8], b[8];
            #pragma unroll
            for (int i = 0; i < 8; i++) a[i] = As[kk][tm * 8 + i];
            #pragma unroll
            for (int j = 0; j < 8; j++) b[j] = Bs[kk][tn * 8 + j];
            #pragma unroll
            for (int i = 0; i < 8; i++)
                #pragma unroll
                for (int j = 0; j < 8; j++)
                    acc[i][j] = fmaf(a[i], b[j], acc[i][j]);
        }
        __syncthreads();
    }
    #pragma unroll
    for (int i = 0; i < 8; i++) {
        float* cp = C + (size_t)(by * BM + tm * 8 + i) * DM + bx * BN + tn * 8;
        #pragma unroll
        for (int j = 0; j < 8; j++) cp[j] = acc[i][j] * scale;
    }
}

__global__ __launch_bounds__(256)
void proj_qw_kernel(const float* __restrict__ Q, const void* __restrict__ Wk,
                    float* __restrict__ QW)
{
    __shared__ float As[BK][BM + PAD];
    __shared__ float Bs[BK][BN + PAD];
    const int isbf = detect_bf16(Wk);
    const int t  = threadIdx.x;
    const int bx = blockIdx.x;
    const int by = blockIdx.y;
    const int tm = t >> 4, tn = t & 15;

    float acc[8][8];
    #pragma unroll
    for (int i = 0; i < 8; i++)
        #pragma unroll
        for (int j = 0; j < 8; j++) acc[i][j] = 0.f;

    const int ar = t >> 1;
    const int ak = (t & 1) * 8;

    for (int kt = 0; kt < DM; kt += BK) {
        const float* ap = Q + (size_t)(by * BM + ar) * DM + kt + ak;
        float4 a0 = *(const float4*)ap;
        float4 a1 = *(const float4*)(ap + 4);
        As[ak + 0][ar] = a0.x; As[ak + 1][ar] = a0.y; As[ak + 2][ar] = a0.z; As[ak + 3][ar] = a0.w;
        As[ak + 4][ar] = a1.x; As[ak + 5][ar] = a1.y; As[ak + 6][ar] = a1.z; As[ak + 7][ar] = a1.w;
        float bv[8];
        load8(Wk, (size_t)(bx * BN + ar) * DM + kt + ak, isbf, bv);
        #pragma unroll
        for (int q = 0; q < 8; q++) Bs[ak + q][ar] = bv[q];
        __syncthreads();
        #pragma unroll
        for (int kk = 0; kk < BK; kk++) {
            float a[8], b[8];
            #pragma unroll
            for (int i = 0; i < 8; i++) a[i] = As[kk][tm * 8 + i];
            #pragma unroll
            for (int j = 0; j < 8; j++) b[j] = Bs[kk][tn * 8 + j];
            #pragma unroll
            for (int i = 0; i < 8; i++)
                #pragma unroll
                for (int j = 0; j < 8; j++)
                    acc[i][j] = fmaf(a[i], b[j], acc[i][j]);
        }
        __syncthreads();
    }
    #pragma unroll
    for (int i = 0; i < 8; i++) {
        float* cp = QW + (size_t)(by * BM + tm * 8 + i) * DM + bx * BN + tn * 8;
        #pragma unroll
        for (int j = 0; j < 8; j++) cp[j] = acc[i][j];
    }
}

template <int PASS>
__global__ __launch_bounds__(256)
void scores_kernel(const float* __restrict__ QW, const void* __restrict__ X,
                   float* __restrict__ pm, float* __restrict__ pl,
                   const float* __restrict__ row_m, const float* __restrict__ row_il,
                   void* __restrict__ out)
{
    __shared__ float As[BK][BM + PAD];
    __shared__ float Bs[BK][BN + PAD];
    __shared__ float red[BM][17];
    __shared__ float rowred[BM];

    const int isbf = detect_bf16(X);
    const int t  = threadIdx.x;
    const int bx = blockIdx.x;
    const int by = blockIdx.y;
    const int tm = t >> 4, tn = t & 15;

    float acc[8][8];
    #pragma unroll
    for (int i = 0; i < 8; i++)
        #pragma unroll
        for (int j = 0; j < 8; j++) acc[i][j] = 0.f;

    const int ar = t >> 1;
    const int ak = (t & 1) * 8;

    for (int kt = 0; kt < DM; kt += BK) {
        const float* ap = QW + (size_t)(by * BM + ar) * DM + kt + ak;
        float4 a0 = *(const float4*)ap;
        float4 a1 = *(const float4*)(ap + 4);
        As[ak + 0][ar] = a0.x; As[ak + 1][ar] = a0.y; As[ak + 2][ar] = a0.z; As[ak + 3][ar] = a0.w;
        As[ak + 4][ar] = a1.x; As[ak + 5][ar] = a1.y; As[ak + 6][ar] = a1.z; As[ak + 7][ar] = a1.w;
        float bv[8];
        load8(X, (size_t)(bx * BN + ar) * DM + kt + ak, isbf, bv);
        #pragma unroll
        for (int q = 0; q < 8; q++) Bs[ak + q][ar] = bv[q];
        __syncthreads();
        #pragma unroll
        for (int kk = 0; kk < BK; kk++) {
            float a[8], b[8];
            #pragma unroll
            for (int i = 0; i < 8; i++) a[i] = As[kk][tm * 8 + i];
            #pragma unroll
            for (int j = 0; j < 8; j++) b[j] = Bs[kk][tn * 8 + j];
            #pragma unroll
            for (int i = 0; i < 8; i++)
                #pragma unroll
                for (int j = 0; j < 8; j++)
                    acc[i][j] = fmaf(a[i], b[j], acc[i][j]);
        }
        __syncthreads();
    }

    if (PASS == 1) {
        #pragma unroll
        for (int i = 0; i < 8; i++) {
            float m = acc[i][0];
            #pragma unroll
            for (int j = 1; j < 8; j++) m = fmaxf(m, acc[i][j]);
            red[tm * 8 + i][tn] = m;
        }
        __syncthreads();
        if (t < BM) {
            float m = red[t][0];
            #pragma unroll
            for (int q = 1; q < 16; q++) m = fmaxf(m, red[t][q]);
            rowred[t] = m;
        }
        __syncthreads();
        #pragma unroll
        for (int i = 0; i < 8; i++) {
            float m = rowred[tm * 8 + i];
            float s = 0.f;
            #pragma unroll
            for (int j = 0; j < 8; j++) s += __expf(acc[i][j] - m);
            red[tm * 8 + i][tn] = s;
        }
        __syncthreads();
        if (t < BM) {
            float s = 0.f;
            #pragma unroll
            for (int q = 0; q < 16; q++) s += red[t][q];
            int grow = by * BM + t;
            pm[(size_t)bx * SEQ + grow] = rowred[t];
            pl[(size_t)bx * SEQ + grow] = s;
        }
    } else {
        #pragma unroll
        for (int i = 0; i < 8; i++) {
            int row = by * BM + tm * 8 + i;
            float m  = row_m[row];
            float il = row_il[row];
            if (isbf) {
                U4 o;
                #pragma unroll
                for (int j = 0; j < 8; j++)
                    o.s[j] = f2bf(__expf(acc[i][j] - m) * il);
                *(uint4*)((ushort_t*)out + (size_t)row * SEQ + bx * BN + tn * 8) = o.u;
            } else {
                float* op = (float*)out + (size_t)row * SEQ + bx * BN + tn * 8;
                float4 o0, o1;
                o0.x = __expf(acc[i][0] - m) * il; o0.y = __expf(acc[i][1] - m) * il;
                o0.z = __expf(acc[i][2] - m) * il; o0.w = __expf(acc[i][3] - m) * il;
                o1.x = __expf(acc[i][4] - m) * il; o1.y = __expf(acc[i][5] - m) * il;
                o1.z = __expf(acc[i][6] - m) * il; o1.w = __expf(acc[i][7] - m) * il;
                *(float4*)op = o0;
                *(float4*)(op + 4) = o1;
            }
        }
    }
}

__global__ __launch_bounds__(256)
void reduce_kernel(const float* __restrict__ pm, const float* __restrict__ pl,
                   float* __restrict__ row_m, float* __restrict__ row_il)
{
    int r = blockIdx.x * 256 + threadIdx.x;
    if (r >= SEQ) return;
    float m = pm[r];
    #pragma unroll
    for (int ti = 1; ti < NCT; ti++) m = fmaxf(m, pm[(size_t)ti * SEQ + r]);
    float l = 0.f;
    #pragma unroll
    for (int ti = 0; ti < NCT; ti++)
        l += pl[(size_t)ti * SEQ + r] * __expf(pm[(size_t)ti * SEQ + r] - m);
    row_m[r]  = m;
    row_il[r] = 1.f / l;
}

// ================= MFMA IN-SITU PROBE (diagnostic; does not affect output) =================

__global__ __launch_bounds__(256)
void transpose_kernel(const ushort_t* __restrict__ in, ushort_t* __restrict__ out)
{
    __shared__ ushort_t t[64][65];
    const int bx = blockIdx.x, by = blockIdx.y;
    const int tr = threadIdx.x >> 2;
    const int tc = (threadIdx.x & 3) * 16;
    #pragma unroll
    for (int j = 0; j < 16; j++)
        t[tr][tc + j] = in[(size_t)(by * 64 + tr) * DM + bx * 64 + tc + j];
    __syncthreads();
    #pragma unroll
    for (int j = 0; j < 16; j++)
        out[(size_t)(bx * 64 + tr) * DM + by * 64 + tc + j] = t[tc + j][tr];
}

// EXACT copy of round-8's gemm_nt<EPI=1> structure (the code under test).
__global__ __launch_bounds__(256)
void mfma_probe_gemm(const ushort_t* __restrict__ A, int Kdim,
                     const ushort_t* __restrict__ B,
                     ushort_t* __restrict__ O, float scale)
{
    __shared__ ushort_t As[128 * 32];
    __shared__ ushort_t Bs[128 * 32];

    const int tid  = threadIdx.x;
    const int bx   = blockIdx.x, by = blockIdx.y;
    const int lane = tid & 63, w = tid >> 6;
    const int wm   = (w >> 1) * 64, wn = (w & 1) * 64;
    const int qr   = lane >> 4, qc = lane & 15;
    const int fk   = qr * 8;

    floatx4 acc[4][4];
    #pragma unroll
    for (int mi = 0; mi < 4; mi++)
        #pragma unroll
        for (int ni = 0; ni < 4; ni++)
            acc[mi][ni] = (floatx4){0.f, 0.f, 0.f, 0.f};

    const size_t aBase = (size_t)(by * 128) * Kdim;
    const size_t bBase = (size_t)(bx * 128) * DM;
    const int r0 = tid >> 2, k0 = (tid & 3) << 3;

    for (int kt = 0; kt < Kdim; kt += 32) {
        uint4 a0 = *(const uint4*)(A + aBase + (size_t)r0 * Kdim + kt + k0);
        uint4 a1 = *(const uint4*)(A + aBase + (size_t)(r0 + 64) * Kdim + kt + k0);
        uint4 b0 = *(const uint4*)(B + bBase + (size_t)r0 * DM + ((kt + k0) & 1023));
        uint4 b1 = *(const uint4*)(B + bBase + (size_t)(r0 + 64) * DM + ((kt + k0) & 1023));
        *(uint4*)(As + tid * 8)         = a0;
        *(uint4*)(As + (tid + 256) * 8) = a1;
        *(uint4*)(Bs + tid * 8)         = b0;
        *(uint4*)(Bs + (tid + 256) * 8) = b1;
        __syncthreads();
        short8 af[4], bfr[4];
        #pragma unroll
        for (int mi = 0; mi < 4; mi++)
            af[mi] = *(const short8*)(As + (wm + mi * 16 + qc) * 32 + fk);
        #pragma unroll
        for (int ni = 0; ni < 4; ni++)
            bfr[ni] = *(const short8*)(Bs + (wn + ni * 16 + qc) * 32 + fk);
        #pragma unroll
        for (int mi = 0; mi < 4; mi++)
            #pragma unroll
            for (int ni = 0; ni < 4; ni++)
                acc[mi][ni] = __builtin_amdgcn_mfma_f32_16x16x32_bf16(
                    af[mi], bfr[ni], acc[mi][ni], 0, 0, 0);
        __syncthreads();
    }

    #pragma unroll
    for (int mi = 0; mi < 4; mi++) {
        #pragma unroll
        for (int rr = 0; rr < 4; rr++) {
            int grow = by * 128 + wm + mi * 16 + qr * 4 + rr;
            ushort_t* orow = O + (size_t)grow * 2048;
            #pragma unroll
            for (int ni = 0; ni < 4; ni++) {
                int gcol = bx * 128 + wn + ni * 16 + qc;
                float v = acc[mi][ni][rr] * scale;
                ushort_t hi = f2bf(v);
                float lo = v - bf2f(hi);
                orow[gcol] = hi;
                orow[1024 + gcol] = f2bf(lo);
            }
        }
    }
}

__global__ __launch_bounds__(256)
void init_flag_kernel(int* flag) {
    if (blockIdx.x == 0 && threadIdx.x == 0) *flag = 0;
}

// compare limb reconstruction (rows 0..2047) vs VALU Q; set flag on mismatch
__global__ __launch_bounds__(256)
void cmp_kernel(const float* __restrict__ Qv, const ushort_t* __restrict__ Qm,
                int* __restrict__ flag)
{
    __shared__ int bad;
    if (threadIdx.x == 0) bad = 0;
    __syncthreads();
    size_t i = (size_t)blockIdx.x * 2048 + threadIdx.x * 8;
    int r = (int)(i >> 10), c = (int)(i & 1023);
    float mx = 0.f;
    #pragma unroll
    for (int j = 0; j < 8; j++) {
        float rec = bf2f(Qm[(size_t)r * 2048 + c + j]) + bf2f(Qm[(size_t)r * 2048 + 1024 + c + j]);
        mx = fmaxf(mx, fabsf(rec - Qv[i + j]));
    }
    if (mx > 1e-3f) atomicOr(&bad, 1);
    __syncthreads();
    if (threadIdx.x == 0 && bad) atomicAdd(flag, 1);
}

// burns ~5 ms ONLY if flag fired -> visible in rocprof/dur_us as the readout
__global__ __launch_bounds__(64)
void spin_kernel(const int* __restrict__ flag, float* __restrict__ sink)
{
    if (*flag == 0) return;
    float v = 1.0f;
    for (int i = 0; i < 3000000; i++) v = fmaf(v, 1.0000000001f, 1e-30f);
    if (v == 123.456f) sink[0] = v;
}

extern "C" void kernel_launch(void* const* d_in, const int* in_sizes, int n_in,
                              void* d_out, int out_size, void* d_ws, size_t ws_size,
                              hipStream_t stream)
{
    const void* x  = d_in[0];
    const void* wq = d_in[1];
    const void* wk = d_in[2];

    // NO-ALIAS layout:
    //   ws[0,16MB):            QW fp32 (live to the end)
    //   ws[16MB,+1.06MB):      pm/pl/rm/ril
    //   ws[18MiB,+8MB):        Qm probe limbs [2048 x 2048] bf16 (diagnostic)
    //   ws[28MiB,+2MB):        wqT (diagnostic)
    //   ws[30MiB,+128B):       flag + sink (diagnostic)
    //   d_out[0,16MB):         Q fp32 scratch — dead before scores<2> writes d_out
    float* QW  = (float*)d_ws;
    float* pm  = QW + (size_t)SEQ * DM;
    float* pl  = pm + (size_t)NCT * SEQ;
    float* rm  = pl + (size_t)NCT * SEQ;
    float* ril = rm + SEQ;
    ushort_t* Qm   = (ushort_t*)((char*)d_ws + (size_t)18 * 1024 * 1024);
    ushort_t* wqT  = (ushort_t*)((char*)d_ws + (size_t)28 * 1024 * 1024);
    int*      flag = (int*)((char*)d_ws + (size_t)30 * 1024 * 1024);
    float*    sink = (float*)((char*)d_ws + (size_t)30 * 1024 * 1024 + 64);
    float* Q   = (float*)d_out;

    dim3 blk(256);
    init_flag_kernel<<<dim3(1), blk, 0, stream>>>(flag);
    // verified pipeline
    proj_q_kernel <<<dim3(DM / BN, SEQ / BM), blk, 0, stream>>>(x, wq, Q, 0.03125f);
    // diagnostic probe: MFMA limb GEMM on rows 0..2047, compare vs Q
    transpose_kernel<<<dim3(16, 16), blk, 0, stream>>>((const ushort_t*)wq, wqT);
    mfma_probe_gemm <<<dim3(8, 16), blk, 0, stream>>>((const ushort_t*)x, 1024, wqT, Qm, 0.03125f);
    cmp_kernel      <<<dim3(1024), blk, 0, stream>>>(Q, Qm, flag);
    // verified pipeline continues
    proj_qw_kernel<<<dim3(DM / BN, SEQ / BM), blk, 0, stream>>>(Q, wk, QW);
    scores_kernel<1><<<dim3(SEQ / BN, SEQ / BM), blk, 0, stream>>>(QW, x, pm, pl, nullptr, nullptr, nullptr);
    reduce_kernel <<<dim3(SEQ / 256), blk, 0, stream>>>(pm, pl, rm, ril);
    scores_kernel<2><<<dim3(SEQ / BN, SEQ / BM), blk, 0, stream>>>(QW, x, nullptr, nullptr, rm, ril, d_out);
    // readout: ~5 ms dispatch iff MFMA probe mismatched
    spin_kernel<<<dim3(1), dim3(64), 0, stream>>>(flag, sink);
}